// Round 7
// baseline (31898.950 us; speedup 1.0000x reference)
//
#include <hip/hip_runtime.h>

// LSTM: I=512, H=2048, O=512, T=4096, batch=1, fp32.
// Phase 1: xz[T][4H] = input @ W_ih^T + (b_ih + b_hh)   (tiled fp32 GEMM)
// Phase 2: persistent plain-launch kernel (256 blocks = 256 CUs co-resident,
//          launch_bounds(256,1)), W_hh register/AGPR-resident.
//          R7: tagged u64 h slots (tag<<32|bits, parity double-buffered) as
//          the ONLY sync object. Per step, WAVE 0 of each block tag-polls
//          all 2048 slots (32/lane, pending-mask, s_sleep pacing) and stages
//          hits into LDS progressively; waves 1-3 sleep at __syncthreads.
//          h is visible at the MALL BEFORE any flag could even issue
//          (flag store must wait for the h-store drain), so this removes
//          producer drain + flag propagate + post-barrier bulk-h RT from
//          R4's critical path, and cuts grid poll-issue rate 4x vs R6.
//          Tag-completeness of h_{t+1} subsumes the grid barrier
//          (overwrite-safety: writer of h_{t+2} observed ALL h_{t+1} tags
//          => every block finished staging h_t; max skew 1 step).
// Phase 3: out = W_lin @ h_T + b_lin (unpacks the tagged h words).

#define TSTEPS 4096
#define HDIM   2048
#define GDIM   8192   // 4H
#define IDIM   512
#define ODIM   512

#define XZ_BYTES ((size_t)TSTEPS * GDIM * sizeof(float))   // 128 MB

typedef unsigned long long u64;

__device__ __forceinline__ float sigmoidf_fast(float x) {
    return 1.0f / (1.0f + __expf(-x));
}
__device__ __forceinline__ float tanhf_fast(float x) {
    return 2.0f / (1.0f + __expf(-2.0f * x)) - 1.0f;
}

// ---------------------------------------------------------------------------
// Phase 1: C[4096][8192] = A[4096][512] * B[8192][512]^T + (bih+bhh)[n]
// 128x128 block tile, BK=16, 256 threads, 8x8 per thread.
// ---------------------------------------------------------------------------
__global__ __launch_bounds__(256) void xz_gemm(
    const float* __restrict__ A, const float* __restrict__ B,
    const float* __restrict__ bih, const float* __restrict__ bhh,
    float* __restrict__ C)
{
    __shared__ float As[16][132];
    __shared__ float Bs[16][132];

    const int tid = threadIdx.x;
    const int m0 = blockIdx.y * 128;
    const int n0 = blockIdx.x * 128;
    const int tx = tid & 15;        // n-direction
    const int ty = tid >> 4;        // m-direction

    const int lrow  = tid >> 1;          // 0..127
    const int kbase = (tid & 1) * 8;     // k offset 0 or 8

    float acc[8][8] = {};

    for (int k0 = 0; k0 < IDIM; k0 += 16) {
        const float4 av0 = *(const float4*)(A + (size_t)(m0 + lrow) * IDIM + k0 + kbase);
        const float4 av1 = *(const float4*)(A + (size_t)(m0 + lrow) * IDIM + k0 + kbase + 4);
        const float4 bv0 = *(const float4*)(B + (size_t)(n0 + lrow) * IDIM + k0 + kbase);
        const float4 bv1 = *(const float4*)(B + (size_t)(n0 + lrow) * IDIM + k0 + kbase + 4);

        __syncthreads();   // previous tile fully consumed
        As[kbase + 0][lrow] = av0.x; As[kbase + 1][lrow] = av0.y;
        As[kbase + 2][lrow] = av0.z; As[kbase + 3][lrow] = av0.w;
        As[kbase + 4][lrow] = av1.x; As[kbase + 5][lrow] = av1.y;
        As[kbase + 6][lrow] = av1.z; As[kbase + 7][lrow] = av1.w;
        Bs[kbase + 0][lrow] = bv0.x; Bs[kbase + 1][lrow] = bv0.y;
        Bs[kbase + 2][lrow] = bv0.z; Bs[kbase + 3][lrow] = bv0.w;
        Bs[kbase + 4][lrow] = bv1.x; Bs[kbase + 5][lrow] = bv1.y;
        Bs[kbase + 6][lrow] = bv1.z; Bs[kbase + 7][lrow] = bv1.w;
        __syncthreads();

#pragma unroll
        for (int kk = 0; kk < 16; ++kk) {
            const float4 a0 = *(const float4*)&As[kk][ty * 8];
            const float4 a1 = *(const float4*)&As[kk][ty * 8 + 4];
            const float4 b0 = *(const float4*)&Bs[kk][tx * 8];
            const float4 b1 = *(const float4*)&Bs[kk][tx * 8 + 4];
            const float ar[8] = {a0.x, a0.y, a0.z, a0.w, a1.x, a1.y, a1.z, a1.w};
            const float br[8] = {b0.x, b0.y, b0.z, b0.w, b1.x, b1.y, b1.z, b1.w};
#pragma unroll
            for (int i = 0; i < 8; ++i)
#pragma unroll
                for (int jj = 0; jj < 8; ++jj)
                    acc[i][jj] = fmaf(ar[i], br[jj], acc[i][jj]);
        }
    }

    float bias[8];
#pragma unroll
    for (int jj = 0; jj < 8; ++jj) {
        const int n = n0 + tx * 8 + jj;
        bias[jj] = bih[n] + bhh[n];
    }
#pragma unroll
    for (int i = 0; i < 8; ++i) {
        float* crow = C + (size_t)(m0 + ty * 8 + i) * GDIM + n0 + tx * 8;
        float4 v0, v1;
        v0.x = acc[i][0] + bias[0]; v0.y = acc[i][1] + bias[1];
        v0.z = acc[i][2] + bias[2]; v0.w = acc[i][3] + bias[3];
        v1.x = acc[i][4] + bias[4]; v1.y = acc[i][5] + bias[5];
        v1.z = acc[i][6] + bias[6]; v1.w = acc[i][7] + bias[7];
        ((float4*)crow)[0] = v0;
        ((float4*)crow)[1] = v1;
    }
}

// ---------------------------------------------------------------------------
// Phase 2: persistent recurrent kernel. 256 blocks x 256 threads, plain
// launch (co-resident at 1 block/CU, launch_bounds(256,1)).
// tid -> j = tid>>5 (h index), gate = (tid>>3)&3 (i,f,g,o), chunk = tid&7.
// Each lane: 256 W_hh weights (64 float4, AGPR-resident) for row = g*H + j,
// k in [chunk*256, chunk*256+256). Owner lane (tid%32==0) holds c_j.
// hq: u64[2][2048] tagged h slots, parity = t&1, tag = t.
// ---------------------------------------------------------------------------
__global__ __launch_bounds__(256, 1) void lstm_rec(
    const float* __restrict__ Whh, const float* __restrict__ xz,
    u64* __restrict__ hq)
{
    // h staged per-step: chunk c at hsh[c*260 .. c*260+256), +4 skew per chunk
    // so matvec ds_read_b128 (8 distinct addrs) is bank-conflict-free.
    __shared__ float hsh[8 * 260];

    const int tidb = threadIdx.x;
    const int tid  = blockIdx.x * 256 + tidb;
    const int j    = tid >> 5;
    const int g    = (tid >> 3) & 3;
    const int ck   = tid & 7;
    const int row  = g * HDIM + j;
    const int wv   = tidb >> 6;    // wave 0..3
    const int ln   = tidb & 63;    // lane

    // one-time weight load into registers/AGPRs (64 MB total across grid)
    const float4* wsrc = (const float4*)(Whh + (size_t)row * HDIM + ck * 256);
    float4 w[64];
#pragma unroll
    for (int i = 0; i < 64; ++i) w[i] = wsrc[i];

    const bool owner = (tid & 31) == 0;
    float cstate = 0.0f;

    float zx = xz[row];   // xz[0][row]

    for (int t = 0; t < TSTEPS; ++t) {
        // ---- WAVE 0: tag-poll h_t slots (32/lane) + stage hits into LDS ----
        if (wv == 0) {
            const u64* hsrc = hq + ((size_t)(t & 1) << 11);
            const unsigned tagexp = (unsigned)t;
            u64 vv[32];
#pragma unroll
            for (int i = 0; i < 32; ++i)
                vv[i] = __hip_atomic_load(hsrc + i * 64 + ln, __ATOMIC_RELAXED,
                                          __HIP_MEMORY_SCOPE_AGENT);
            unsigned pend = 0xffffffffu;
            unsigned spins = 0;
            for (;;) {
                unsigned newpend = 0;
#pragma unroll
                for (int i = 0; i < 32; ++i) {
                    if (pend & (1u << i)) {
                        if ((unsigned)(vv[i] >> 32) == tagexp) {
                            const int s = i * 64 + ln;
                            hsh[(s >> 8) * 260 + (s & 255)] =
                                __uint_as_float((unsigned)vv[i]);
                        } else {
                            newpend |= (1u << i);
                        }
                    }
                }
                pend = newpend;
                if (__all(pend == 0)) break;       // wave-coherent exit
                __builtin_amdgcn_s_sleep(1);       // pace the re-poll
#pragma unroll
                for (int i = 0; i < 32; ++i)
                    if (pend & (1u << i))
                        vv[i] = __hip_atomic_load(hsrc + i * 64 + ln,
                                                  __ATOMIC_RELAXED,
                                                  __HIP_MEMORY_SCOPE_AGENT);
                if (++spins > (1u << 22)) break;   // fail fast, no hang
            }
        }
        __syncthreads();   // h_t fully staged in LDS

        // ---- matvec from LDS (conflict-free b128 reads) ----
        const float4* hr = (const float4*)(hsh + ck * 260);
        float a0 = 0.f, a1 = 0.f, a2 = 0.f, a3 = 0.f;
#pragma unroll
        for (int i = 0; i < 64; ++i) {
            const float4 h4 = hr[i];
            a0 = fmaf(w[i].x, h4.x, a0);
            a1 = fmaf(w[i].y, h4.y, a1);
            a2 = fmaf(w[i].z, h4.z, a2);
            a3 = fmaf(w[i].w, h4.w, a3);
        }
        float d = (a0 + a1) + (a2 + a3);
        d += __shfl_xor(d, 1);
        d += __shfl_xor(d, 2);
        d += __shfl_xor(d, 4);
        const float z  = d + zx;
        const float zf = __shfl_xor(z, 8);    // gate f partner
        const float zg = __shfl_xor(z, 16);   // gate g partner
        const float zo = __shfl_xor(z, 24);   // gate o partner

        if (owner) {   // lane has (i,f,g,o) for its j in (z, zf, zg, zo)
            const float ig = sigmoidf_fast(z);
            const float fg = sigmoidf_fast(zf);
            const float gg = tanhf_fast(zg);
            const float og = sigmoidf_fast(zo);
            cstate = fmaf(fg, cstate, ig * gg);
            const float hval = og * tanhf_fast(cstate);
            const u64 pack = ((u64)(unsigned)(t + 1) << 32) |
                             (u64)__float_as_uint(hval);
            // publish h_{t+1}[j]: data + tag in one MALL write
            __hip_atomic_store(hq + ((size_t)((t + 1) & 1) << 11) + j, pack,
                               __ATOMIC_RELAXED, __HIP_MEMORY_SCOPE_AGENT);
        }

        // prefetch next xz row (read-only, normal cached load)
        const int tn = (t + 1 < TSTEPS) ? (t + 1) : (TSTEPS - 1);
        zx = xz[(size_t)tn * GDIM + row];

        __syncthreads();   // all hsh reads done before wave 0 restages;
                           // also drains owner stores before next poll round
    }
}

// ---------------------------------------------------------------------------
// Phase 3: out[512] = W_lin[512][2048] @ h_T + b_lin. One wave per output.
// h_T = h_4096 lives in hq parity 0, packed (tag 4096 in high bits).
// ---------------------------------------------------------------------------
__global__ __launch_bounds__(256) void final_linear(
    const float* __restrict__ Wlin, const float* __restrict__ blin,
    const u64* __restrict__ hq, float* __restrict__ out)
{
    const int wid  = (blockIdx.x * 256 + threadIdx.x) >> 6;   // 0..511
    const int lane = threadIdx.x & 63;
    const float4* wr = (const float4*)(Wlin + (size_t)wid * HDIM);
    float acc = 0.f;
#pragma unroll
    for (int i = 0; i < 8; ++i) {
        const int f = (lane + 64 * i) * 4;       // float index base
        const float4 w4 = wr[lane + 64 * i];
        const float hx = __uint_as_float((unsigned)hq[f + 0]);
        const float hy = __uint_as_float((unsigned)hq[f + 1]);
        const float hz = __uint_as_float((unsigned)hq[f + 2]);
        const float hw = __uint_as_float((unsigned)hq[f + 3]);
        acc += w4.x * hx + w4.y * hy + w4.z * hz + w4.w * hw;
    }
#pragma unroll
    for (int off = 32; off > 0; off >>= 1) acc += __shfl_down(acc, off);
    if (lane == 0) out[wid] = acc + blin[wid];
}

extern "C" void kernel_launch(void* const* d_in, const int* in_sizes, int n_in,
                              void* d_out, int out_size, void* d_ws, size_t ws_size,
                              hipStream_t stream) {
    const float* input = (const float*)d_in[0];   // [4096][512]
    const float* Wih   = (const float*)d_in[1];   // [8192][512]
    const float* Whh   = (const float*)d_in[2];   // [8192][2048]
    const float* bih   = (const float*)d_in[3];   // [8192]
    const float* bhh   = (const float*)d_in[4];   // [8192]
    const float* Wlin  = (const float*)d_in[5];   // [512][2048]
    const float* blin  = (const float*)d_in[6];   // [512]
    float* out = (float*)d_out;                   // [512]

    char* ws = (char*)d_ws;
    float* xz = (float*)ws;                          // 128 MB
    u64*   hq = (u64*)(ws + XZ_BYTES);               // 2 x 2048 x 8 B = 32 KB

    // zero tagged h buffers: tag 0 + h=0.0f == valid h_0 (ws poisoned 0xAA)
    hipMemsetAsync(hq, 0, 2 * HDIM * sizeof(u64), stream);

    dim3 ggrid(GDIM / 128, TSTEPS / 128);   // (64, 32)
    xz_gemm<<<ggrid, 256, 0, stream>>>(input, Wih, bih, bhh, xz);

    // plain launch: 256 blocks, 1 block/CU => all co-resident on 256 CUs.
    lstm_rec<<<dim3(256), dim3(256), 0, stream>>>(Whh, xz, hq);

    final_linear<<<ODIM / 4, 256, 0, stream>>>(Wlin, blin, hq, out);
}

// Round 8
// 18026.501 us; speedup vs baseline: 1.7696x; 1.7696x over previous
//
#include <hip/hip_runtime.h>

// LSTM: I=512, H=2048, O=512, T=4096, batch=1, fp32.
// Phase 1: xz[T][4H] = input @ W_ih^T + (b_ih + b_hh)   (tiled fp32 GEMM)
// Phase 2: persistent plain-launch kernel (256 blocks = 256 CUs co-resident,
//          launch_bounds(256,1)), W_hh register/AGPR-resident.
//          R8 = R4's proven flag scheme (h loaded exactly ONCE; flags are
//          the only polled lines — R5/R6/R7 showed polling the h lines
//          themselves always loses) with a shorter critical path:
//          leading wait (flag >= t at top of step), quarter-affine polling
//          (wave q polls the 64 flags of the blocks producing its h-quarter,
//          1 flag/lane, then immediately loads its 512 h values), and
//          2 syncthreads/step instead of 4.
// Phase 3: out = W_lin @ h_T + b_lin.

#define TSTEPS 4096
#define HDIM   2048
#define GDIM   8192   // 4H
#define IDIM   512
#define ODIM   512

#define XZ_BYTES ((size_t)TSTEPS * GDIM * sizeof(float))   // 128 MB
#define FLAG_STRIDE 16   // unsigned slots per block flag: 64B line pitch

__device__ __forceinline__ float sigmoidf_fast(float x) {
    return 1.0f / (1.0f + __expf(-x));
}
__device__ __forceinline__ float tanhf_fast(float x) {
    return 2.0f / (1.0f + __expf(-2.0f * x)) - 1.0f;
}

// ---------------------------------------------------------------------------
// Phase 1: C[4096][8192] = A[4096][512] * B[8192][512]^T + (bih+bhh)[n]
// 128x128 block tile, BK=16, 256 threads, 8x8 per thread.
// ---------------------------------------------------------------------------
__global__ __launch_bounds__(256) void xz_gemm(
    const float* __restrict__ A, const float* __restrict__ B,
    const float* __restrict__ bih, const float* __restrict__ bhh,
    float* __restrict__ C)
{
    __shared__ float As[16][132];
    __shared__ float Bs[16][132];

    const int tid = threadIdx.x;
    const int m0 = blockIdx.y * 128;
    const int n0 = blockIdx.x * 128;
    const int tx = tid & 15;        // n-direction
    const int ty = tid >> 4;        // m-direction

    const int lrow  = tid >> 1;          // 0..127
    const int kbase = (tid & 1) * 8;     // k offset 0 or 8

    float acc[8][8] = {};

    for (int k0 = 0; k0 < IDIM; k0 += 16) {
        const float4 av0 = *(const float4*)(A + (size_t)(m0 + lrow) * IDIM + k0 + kbase);
        const float4 av1 = *(const float4*)(A + (size_t)(m0 + lrow) * IDIM + k0 + kbase + 4);
        const float4 bv0 = *(const float4*)(B + (size_t)(n0 + lrow) * IDIM + k0 + kbase);
        const float4 bv1 = *(const float4*)(B + (size_t)(n0 + lrow) * IDIM + k0 + kbase + 4);

        __syncthreads();   // previous tile fully consumed
        As[kbase + 0][lrow] = av0.x; As[kbase + 1][lrow] = av0.y;
        As[kbase + 2][lrow] = av0.z; As[kbase + 3][lrow] = av0.w;
        As[kbase + 4][lrow] = av1.x; As[kbase + 5][lrow] = av1.y;
        As[kbase + 6][lrow] = av1.z; As[kbase + 7][lrow] = av1.w;
        Bs[kbase + 0][lrow] = bv0.x; Bs[kbase + 1][lrow] = bv0.y;
        Bs[kbase + 2][lrow] = bv0.z; Bs[kbase + 3][lrow] = bv0.w;
        Bs[kbase + 4][lrow] = bv1.x; Bs[kbase + 5][lrow] = bv1.y;
        Bs[kbase + 6][lrow] = bv1.z; Bs[kbase + 7][lrow] = bv1.w;
        __syncthreads();

#pragma unroll
        for (int kk = 0; kk < 16; ++kk) {
            const float4 a0 = *(const float4*)&As[kk][ty * 8];
            const float4 a1 = *(const float4*)&As[kk][ty * 8 + 4];
            const float4 b0 = *(const float4*)&Bs[kk][tx * 8];
            const float4 b1 = *(const float4*)&Bs[kk][tx * 8 + 4];
            const float ar[8] = {a0.x, a0.y, a0.z, a0.w, a1.x, a1.y, a1.z, a1.w};
            const float br[8] = {b0.x, b0.y, b0.z, b0.w, b1.x, b1.y, b1.z, b1.w};
#pragma unroll
            for (int i = 0; i < 8; ++i)
#pragma unroll
                for (int jj = 0; jj < 8; ++jj)
                    acc[i][jj] = fmaf(ar[i], br[jj], acc[i][jj]);
        }
    }

    float bias[8];
#pragma unroll
    for (int jj = 0; jj < 8; ++jj) {
        const int n = n0 + tx * 8 + jj;
        bias[jj] = bih[n] + bhh[n];
    }
#pragma unroll
    for (int i = 0; i < 8; ++i) {
        float* crow = C + (size_t)(m0 + ty * 8 + i) * GDIM + n0 + tx * 8;
        float4 v0, v1;
        v0.x = acc[i][0] + bias[0]; v0.y = acc[i][1] + bias[1];
        v0.z = acc[i][2] + bias[2]; v0.w = acc[i][3] + bias[3];
        v1.x = acc[i][4] + bias[4]; v1.y = acc[i][5] + bias[5];
        v1.z = acc[i][6] + bias[6]; v1.w = acc[i][7] + bias[7];
        ((float4*)crow)[0] = v0;
        ((float4*)crow)[1] = v1;
    }
}

// ---------------------------------------------------------------------------
// Phase 2: persistent recurrent kernel. 256 blocks x 256 threads, plain
// launch (co-resident at 1 block/CU, launch_bounds(256,1)).
// tid -> j = tid>>5 (h index), gate = (tid>>3)&3 (i,f,g,o), chunk = tid&7.
// Each lane: 256 W_hh weights (64 float4, AGPR-resident) for row = g*H + j,
// k in [chunk*256, chunk*256+256). Owner lane (tid%32==0) holds c_j.
// Block b produces j in [8b, 8b+8); h-quarter q produced by blocks
// [64q, 64q+64). flags[b] = number of steps block b has completed.
// Leading wait: at top of step t, wave q waits for flags of its 64 source
// blocks >= t, then loads its 512 h values once. Overwrite safety: h_{t+2}
// (parity of h_t) is stored only after this block saw all flags >= t+1,
// i.e. every block already consumed h_t. Max skew 1 step.
// ---------------------------------------------------------------------------
__global__ __launch_bounds__(256, 1) void lstm_rec(
    const float* __restrict__ Whh, const float* __restrict__ xz,
    float* __restrict__ hbuf, unsigned* __restrict__ flags)
{
    // h staged per-step: chunk c at hsh[c*260 .. c*260+256), +4 skew per chunk
    // so matvec ds_read_b128 (8 distinct addrs) is bank-conflict-free.
    __shared__ float hsh[8 * 260];

    const int tidb = threadIdx.x;
    const int tid  = blockIdx.x * 256 + tidb;
    const int j    = tid >> 5;
    const int g    = (tid >> 3) & 3;
    const int ck   = tid & 7;
    const int row  = g * HDIM + j;
    const int wv   = tidb >> 6;    // wave 0..3 == h-quarter this wave handles
    const int ln   = tidb & 63;    // lane

    // one-time weight load into registers/AGPRs (64 MB total across grid)
    const float4* wsrc = (const float4*)(Whh + (size_t)row * HDIM + ck * 256);
    float4 w[64];
#pragma unroll
    for (int i = 0; i < 64; ++i) w[i] = wsrc[i];

    const bool owner = (tid & 31) == 0;
    float cstate = 0.0f;

    // this wave's source-block flag (1 per lane) and h slots (8 per lane)
    const unsigned* myflag = flags + (size_t)(wv * 64 + ln) * FLAG_STRIDE;

    float zx = xz[row];   // xz[0][row]

    for (int t = 0; t < TSTEPS; ++t) {
        // ---- leading wait: my quarter's 64 producers finished step t-1 ----
        {
            const unsigned need = (unsigned)t;
            unsigned spins = 0;
            while (__hip_atomic_load(myflag, __ATOMIC_RELAXED,
                                     __HIP_MEMORY_SCOPE_AGENT) < need) {
                __builtin_amdgcn_s_sleep(1);
                if (++spins > (1u << 22)) break;   // fail fast, no hang
            }
        }

        // ---- load my 512-value h-quarter ONCE (coalesced, 8/lane) ----
        const float* hsrc = hbuf + ((t & 1) << 11) + wv * 512;
        float hv[8];
#pragma unroll
        for (int m = 0; m < 8; ++m)
            hv[m] = __hip_atomic_load(hsrc + m * 64 + ln, __ATOMIC_RELAXED,
                                      __HIP_MEMORY_SCOPE_AGENT);
#pragma unroll
        for (int m = 0; m < 8; ++m) {
            const int k = wv * 512 + m * 64 + ln;
            hsh[(k >> 8) * 260 + (k & 255)] = hv[m];
        }
        __syncthreads();   // all quarters staged

        // ---- matvec from LDS (conflict-free b128 reads) ----
        const float4* hr = (const float4*)(hsh + ck * 260);
        float a0 = 0.f, a1 = 0.f, a2 = 0.f, a3 = 0.f;
#pragma unroll
        for (int i = 0; i < 64; ++i) {
            const float4 h4 = hr[i];
            a0 = fmaf(w[i].x, h4.x, a0);
            a1 = fmaf(w[i].y, h4.y, a1);
            a2 = fmaf(w[i].z, h4.z, a2);
            a3 = fmaf(w[i].w, h4.w, a3);
        }
        float d = (a0 + a1) + (a2 + a3);
        d += __shfl_xor(d, 1);
        d += __shfl_xor(d, 2);
        d += __shfl_xor(d, 4);
        const float z  = d + zx;
        const float zf = __shfl_xor(z, 8);    // gate f partner
        const float zg = __shfl_xor(z, 16);   // gate g partner
        const float zo = __shfl_xor(z, 24);   // gate o partner

        if (owner) {   // lane has (i,f,g,o) for its j in (z, zf, zg, zo)
            const float ig = sigmoidf_fast(z);
            const float fg = sigmoidf_fast(zf);
            const float gg = tanhf_fast(zg);
            const float og = sigmoidf_fast(zo);
            cstate = fmaf(fg, cstate, ig * gg);
            const float hval = og * tanhf_fast(cstate);
            __hip_atomic_store(hbuf + (((t + 1) & 1) << 11) + j, hval,
                               __ATOMIC_RELAXED, __HIP_MEMORY_SCOPE_AGENT);
        }

        // prefetch next xz row (read-only, normal cached load)
        const int tn = (t + 1 < TSTEPS) ? (t + 1) : (TSTEPS - 1);
        zx = xz[(size_t)tn * GDIM + row];

        // trailing sync: (a) hsh reads done before next-step restage,
        // (b) compiler-emitted vmcnt(0) drain => owner h stores are
        //     MALL-visible before the flag store below.
        __syncthreads();
        if (tidb == 0)
            __hip_atomic_store(flags + (size_t)blockIdx.x * FLAG_STRIDE,
                               (unsigned)(t + 1), __ATOMIC_RELAXED,
                               __HIP_MEMORY_SCOPE_AGENT);
    }
}

// ---------------------------------------------------------------------------
// Phase 3: out[512] = W_lin[512][2048] @ h_T + b_lin. One wave per output.
// h_T = h_4096 lives in hbuf parity 0 (4096 & 1 == 0).
// ---------------------------------------------------------------------------
__global__ __launch_bounds__(256) void final_linear(
    const float* __restrict__ Wlin, const float* __restrict__ blin,
    const float* __restrict__ hT, float* __restrict__ out)
{
    const int wid  = (blockIdx.x * 256 + threadIdx.x) >> 6;   // 0..511
    const int lane = threadIdx.x & 63;
    const float4* wr = (const float4*)(Wlin + (size_t)wid * HDIM);
    const float4* hp = (const float4*)hT;
    float acc = 0.f;
#pragma unroll
    for (int i = 0; i < 8; ++i) {
        const float4 w4 = wr[lane + 64 * i];
        const float4 h4 = hp[lane + 64 * i];
        acc += w4.x * h4.x + w4.y * h4.y + w4.z * h4.z + w4.w * h4.w;
    }
#pragma unroll
    for (int off = 32; off > 0; off >>= 1) acc += __shfl_down(acc, off);
    if (lane == 0) out[wid] = acc + blin[wid];
}

extern "C" void kernel_launch(void* const* d_in, const int* in_sizes, int n_in,
                              void* d_out, int out_size, void* d_ws, size_t ws_size,
                              hipStream_t stream) {
    const float* input = (const float*)d_in[0];   // [4096][512]
    const float* Wih   = (const float*)d_in[1];   // [8192][512]
    const float* Whh   = (const float*)d_in[2];   // [8192][2048]
    const float* bih   = (const float*)d_in[3];   // [8192]
    const float* bhh   = (const float*)d_in[4];   // [8192]
    const float* Wlin  = (const float*)d_in[5];   // [512][2048]
    const float* blin  = (const float*)d_in[6];   // [512]
    float* out = (float*)d_out;                   // [512]

    char* ws = (char*)d_ws;
    float*    xz    = (float*)ws;                                   // 128 MB
    float*    hbuf  = (float*)(ws + XZ_BYTES);                      // 2 x 2048 fp32
    unsigned* flags = (unsigned*)(ws + XZ_BYTES + 2 * HDIM * sizeof(float)); // 256*64B

    // zero h buffers + flags (ws is poisoned 0xAA before every launch);
    // flags=0 == "0 steps completed" == h_0 (zeros) valid.
    hipMemsetAsync(hbuf, 0,
                   2 * HDIM * sizeof(float) + 256 * FLAG_STRIDE * sizeof(unsigned),
                   stream);

    dim3 ggrid(GDIM / 128, TSTEPS / 128);   // (64, 32)
    xz_gemm<<<ggrid, 256, 0, stream>>>(input, Wih, bih, bhh, xz);

    // plain launch: 256 blocks, 1 block/CU => all co-resident on 256 CUs.
    lstm_rec<<<dim3(256), dim3(256), 0, stream>>>(Whh, xz, hbuf, flags);

    final_linear<<<ODIM / 4, 256, 0, stream>>>(Wlin, blin, hbuf, out);
}